// Round 5
// baseline (132.140 us; speedup 1.0000x reference)
//
#include <hip/hip_runtime.h>
#include <math.h>

#define DEVI __device__ __forceinline__

static constexpr float KD[10] = {
  0.027333068345077982f,  0.029519490925774643f, -0.039134249302383094f,
  0.1993975339773936f,    0.7234076904024206f,    0.6339789634582119f,
  0.01660210576452232f,  -0.17532808990845047f,  -0.021101834024758855f,
  0.019538882735286728f};

// ---------- workspace layout (float offsets) ----------
#define CE_OFF     0         // 105000 floats (ce per pixel, 0 for non-negatives)
#define ACC_OFF    105000    // 3 x 8 floats (written by select_bin after partial-reduce)
#define SUMGT_OFF  105024    // 3 floats
#define CCNT_OFF   105027    // 3 uints
#define STATE_OFF  105030    // 3 x 8 words: [0]=ibin [1]=rem [2]=kf(float) [3]=k_take
#define HIST_OFF   105056    // 3 x 65536 uints (16B-aligned)
#define CBUF_OFF   301664    // 3 x CAP floats
#define CAP        8192
#define PART_OFF   326240    // 3 x 15000 floats (per-wave-block partials)
#define PART_STRIDE 15000    // 2500 slots x 6

// zero hist + small state + out; replaces the slow ROCclr fillBuffer (42us for 786KB)
__global__ void zero_kernel(float* __restrict__ ws, float* __restrict__ out) {
  int i = blockIdx.x * 256 + threadIdx.x;       // 192*256 = 49152 uint4 = 196608 dwords
  uint4* h4 = (uint4*)(ws + HIST_OFF);
  h4[i] = make_uint4(0u, 0u, 0u, 0u);
  if (blockIdx.x == 0) {
    if (threadIdx.x < 56) ws[ACC_OFF + threadIdx.x] = 0.f;   // acc+sumgt+ccnt+state+pad
    if (threadIdx.x < 3) out[threadIdx.x] = 0.f;
  }
}

// waverec3 on a 20-vector + offset, accumulating smooth_l1 over the 100 outputs.
// Stage 1 materializes a1[31]; stages 2+3 fused with a 5-wide rolling window.
DEVI float recon_sl1(const float* c, float off) {
  float a1[31];
#pragma unroll
  for (int o = 0; o < 31; ++o) {
    int b = o >> 1;
    if (o & 1)
      a1[o] = KD[0]*c[b] + KD[2]*c[b+1] + KD[4]*c[b+2] + KD[6]*c[b+3] + KD[8]*c[b+4];
    else
      a1[o] = KD[1]*c[b] + KD[3]*c[b+1] + KD[5]*c[b+2] + KD[7]*c[b+3] + KD[9]*c[b+4];
  }
  float acc = 0.f;
  float w0 = 0.f, w1 = 0.f, w2 = 0.f, w3 = 0.f, w4 = 0.f;
#pragma unroll
  for (int j = 0; j < 54; ++j) {
    int b = j >> 1;
    float aj;
    if (j & 1)
      aj = KD[0]*a1[b] + KD[2]*a1[b+1] + KD[4]*a1[b+2] + KD[6]*a1[b+3] + KD[8]*a1[b+4];
    else
      aj = KD[1]*a1[b] + KD[3]*a1[b+1] + KD[5]*a1[b+2] + KD[7]*a1[b+3] + KD[9]*a1[b+4];
    w0 = w1; w1 = w2; w2 = w3; w3 = w4; w4 = aj;
    if (j >= 4) {
      float ve = KD[1]*w0 + KD[3]*w1 + KD[5]*w2 + KD[7]*w3 + KD[9]*w4 + off;
      float vo = KD[0]*w0 + KD[2]*w1 + KD[4]*w2 + KD[6]*w3 + KD[8]*w4 + off;
      float ae = fabsf(ve);
      acc += (ae < 1.f) ? 0.5f * ve * ve : ae - 0.5f;
      float ao = fabsf(vo);
      acc += (ao < 1.f) ? 0.5f * vo * vo : ao - 0.5f;
    }
  }
  return acc;
}

DEVI float wave_sum(float v) {
#pragma unroll
  for (int d = 32; d; d >>= 1) v += __shfl_down(v, d);
  return v;
}

DEVI float block_sum(float v, float* sh) {
  int lane = threadIdx.x & 63, wid = threadIdx.x >> 6;
  v = wave_sum(v);
  if (lane == 0) sh[wid] = v;
  __syncthreads();
  if (threadIdx.x == 0) {
    float s = 0.f;
    int nw = blockDim.x >> 6;
    for (int w = 0; w < nw; ++w) s += sh[w];
    sh[0] = s;
  }
  __syncthreads();
  float r = sh[0];
  __syncthreads();
  return r;
}

// inclusive suffix sum across 256 threads; sh must be int[256]
DEVI int suffix_scan_256(int v, int* sh) {
  int t = threadIdx.x;
  sh[t] = v;
  __syncthreads();
#pragma unroll
  for (int off = 1; off < 256; off <<= 1) {
    int x = (t + off < 256) ? sh[t + off] : 0;
    __syncthreads();
    sh[t] += x;
    __syncthreads();
  }
  return sh[t];
}

// 64-thread (1-wave) blocks: no LDS, no barrier; partials per wave-block slot:
// [0]=cnt_pos [1]=cnt_neg [2]=sum_ce_pos [3]=sum_tcl_ttm [4]=sum_tcl_negm [5]=sum_ttm_pp
// blockIdx.y = axis (0: x-contour + all CE/mask work; 1: y-contour only)
__global__ void pixel_kernel(const float* __restrict__ cls, const float* __restrict__ reg,
                             const float* __restrict__ gt, float* __restrict__ ceArr,
                             float* __restrict__ part, unsigned* __restrict__ hist,
                             int M, int HW) {
  int p = blockIdx.x * 64 + threadIdx.x;
  int axis = blockIdx.y;
  float cnt_pos = 0.f, cnt_neg = 0.f, s_ce_pos = 0.f, s_tcl_ttm = 0.f, s_tcl_negm = 0.f;
  float s_ttm_pp = 0.f;
  if (p < M) {
    int n = p / HW, hw = p % HW;
    const float* gb = gt  + (size_t)n * 45 * HW + hw;
    const float* rb = reg + (size_t)n * 42 * HW + hw;
    float tr = gb[0], train = gb[2*(size_t)HW];
    float ttm = tr * train;

    if (axis == 0) {
      const float* cb = cls + (size_t)n * 4 * HW + hw;
      float l0 = cb[0], l1 = cb[(size_t)HW], l2 = cb[2*(size_t)HW], l3 = cb[3*(size_t)HW];
      float tcl = gb[(size_t)HW];

      float m1 = fmaxf(l0, l1);
      float lse1 = m1 + logf(expf(l0 - m1) + expf(l1 - m1));
      float ce_tr = lse1 - ((tr > 0.5f) ? l1 : l0);
      float m2 = fmaxf(l2, l3);
      float lse2 = m2 + logf(expf(l2 - m2) + expf(l3 - m2));
      float ce_tcl = lse2 - ((tcl > 0.5f) ? l3 : l2);

      bool pos = ttm > 0.f;
      bool neg = ((1.f - tr) * train) > 0.f;
      float cev = neg ? ce_tr : 0.f;
      ceArr[p] = cev;
      if (neg) atomicAdd(&hist[__float_as_uint(cev) >> 16], 1u);

      cnt_pos = pos ? 1.f : 0.f;
      cnt_neg = neg ? 1.f : 0.f;
      s_ce_pos = pos ? ce_tr : 0.f;
      s_tcl_ttm = ce_tcl * ttm;
      s_tcl_negm = ce_tcl * (1.f - ttm);
    }

    // contour (this axis): linearity => reconstruct the coefficient difference
    int rc0 = (axis == 0) ? 0 : 21;
    int gc0 = (axis == 0) ? 3 : 24;
    float d[20];
#pragma unroll
    for (int c = 0; c < 20; ++c) d[c] = rb[(size_t)(rc0 + c) * HW] - gb[(size_t)(gc0 + c) * HW];
    float dc = rb[(size_t)(rc0 + 20) * HW] - gb[(size_t)(gc0 + 20) * HW];
    s_ttm_pp = ttm * recon_sl1(d, dc);
  }

  cnt_pos = wave_sum(cnt_pos);
  cnt_neg = wave_sum(cnt_neg);
  s_ce_pos = wave_sum(s_ce_pos);
  s_tcl_ttm = wave_sum(s_tcl_ttm);
  s_tcl_negm = wave_sum(s_tcl_negm);
  s_ttm_pp = wave_sum(s_ttm_pp);
  if (threadIdx.x == 0) {
    float* p6 = part + (size_t)(axis * gridDim.x + blockIdx.x) * 6;
    p6[0] = cnt_pos; p6[1] = cnt_neg; p6[2] = s_ce_pos;
    p6[3] = s_tcl_ttm; p6[4] = s_tcl_negm; p6[5] = s_ttm_pp;
  }
}

// one block per scale: reduce partials -> acc, then find the 16-bit bin
// holding the k-th largest negative CE
__global__ void select_bin_kernel(float* __restrict__ ws) {
  int s = blockIdx.x, t = threadIdx.x;
  float* acc = ws + ACC_OFF + s * 8;
  int* st = (int*)(ws + STATE_OFF) + s * 8;
  const unsigned* hist = (const unsigned*)(ws + HIST_OFF) + s * 65536;
  const float* part = ws + PART_OFF + s * PART_STRIDE;
  int npart = (s == 0) ? 2500 : (s == 1 ? 626 : 158);

  __shared__ int sh[256];
  __shared__ int sel[2];
  __shared__ float red[4];

  float a0 = 0.f, a1 = 0.f, a2 = 0.f, a3 = 0.f, a4 = 0.f, a5 = 0.f;
  for (int i = t; i < npart; i += 256) {
    const float* p6 = part + (size_t)i * 6;
    a0 += p6[0]; a1 += p6[1]; a2 += p6[2]; a3 += p6[3]; a4 += p6[4]; a5 += p6[5];
  }
  a0 = block_sum(a0, red);
  a1 = block_sum(a1, red);
  a2 = block_sum(a2, red);
  a3 = block_sum(a3, red);
  a4 = block_sum(a4, red);
  a5 = block_sum(a5, red);
  if (t == 0) { acc[0] = a0; acc[1] = a1; acc[2] = a2; acc[3] = a3; acc[4] = a4; acc[5] = a5; }

  float cnt_pos = a0, cnt_negf = a1;
  int cnt_neg = (int)cnt_negf;
  float kf = (cnt_pos > 0.f) ? fminf(cnt_negf, floorf(3.f * cnt_pos)) : 100.f;
  int k_take = min((int)kf, cnt_neg);

  int ibin, rem;
  if (k_take >= cnt_neg) { ibin = -1; rem = 0; }          // take all negatives
  else if (k_take <= 0)  { ibin = 65536; rem = 0; }       // take none
  else {
    int psum = 0;
    const uint4* h4 = (const uint4*)(hist + t * 256);
#pragma unroll 8
    for (int j = 0; j < 64; ++j) { uint4 u = h4[j]; psum += (int)(u.x + u.y + u.z + u.w); }
    int suf = suffix_scan_256(psum, sh);
    int above = suf - psum;
    if (suf >= k_take && above < k_take) { sel[0] = t; sel[1] = k_take - above; }
    __syncthreads();
    int chunk = sel[0], remc = sel[1];
    __syncthreads();
    int h = (int)hist[chunk * 256 + t];
    suf = suffix_scan_256(h, sh);
    above = suf - h;
    if (suf >= remc && above < remc) { sel[0] = chunk * 256 + t; sel[1] = remc - above; }
    __syncthreads();
    ibin = sel[0]; rem = sel[1];
  }
  if (t == 0) {
    st[0] = ibin;
    st[1] = rem;
    ((float*)st)[2] = kf;
    st[3] = k_take;
  }
}

// grid-wide: sum ce strictly above bin; compact in-bin values
__global__ void compact_kernel(float* __restrict__ ws) {
  int s = blockIdx.y;
  int M   = (s == 0) ? 80000 : (s == 1 ? 20000 : 5000);
  int off = (s == 0) ? 0     : (s == 1 ? 80000 : 100000);
  const int* st = (const int*)(ws + STATE_OFF) + s * 8;
  int ibin = st[0];
  float sum = 0.f;
  __shared__ float red[4];
  if (ibin < 65536) {
    const float* ce = ws + off;
    unsigned* ccnt = (unsigned*)(ws + CCNT_OFF) + s;
    float* cbuf = ws + CBUF_OFF + s * CAP;
    for (int i = blockIdx.x * blockDim.x + threadIdx.x; i < M; i += gridDim.x * blockDim.x) {
      float v = ce[i];
      int bin = (int)(__float_as_uint(v) >> 16);
      if (bin > ibin) sum += v;
      else if (bin == ibin) {
        unsigned idx = atomicAdd(ccnt, 1u);
        if (idx < CAP) cbuf[idx] = v;
      }
    }
  }
  sum = block_sum(sum, red);
  if (threadIdx.x == 0 && sum != 0.f) atomicAdd(ws + SUMGT_OFF + s, sum);
}

// one block per scale: exact k-th value within the bin (two 8-bit LDS radix passes), assemble losses
__global__ void final_kernel(float* __restrict__ ws, float* __restrict__ out) {
  int s = blockIdx.x, t = threadIdx.x;
  int M = (s == 0) ? 80000 : (s == 1 ? 20000 : 5000);
  const float* acc = ws + ACC_OFF + s * 8;
  const int* st = (const int*)(ws + STATE_OFF) + s * 8;

  __shared__ int hist[256];
  __shared__ int sh[256];
  __shared__ int sel[2];
  __shared__ float red[8];

  float cnt_pos = acc[0];
  float s_ce_pos = acc[2], s_tcl_ttm = acc[3], s_tcl_negm = acc[4], s_ttm_pp = acc[5];
  int ibin = st[0], rem = st[1];
  float kf = ((const float*)st)[2];
  float loss_neg = ws[SUMGT_OFF + s];

  if (rem > 0) {
    int cnt = min((int)((unsigned*)(ws + CCNT_OFF))[s], CAP);
    const float* cbuf = ws + CBUF_OFF + s * CAP;

    hist[t] = 0; __syncthreads();
    for (int i = t; i < cnt; i += 256)
      atomicAdd(&hist[(__float_as_uint(cbuf[i]) >> 8) & 255u], 1);
    __syncthreads();
    int h = hist[t];
    int suf = suffix_scan_256(h, sh);
    int above = suf - h;
    if (suf >= rem && above < rem) { sel[0] = t; sel[1] = rem - above; }
    __syncthreads();
    int b1 = sel[0], rem1 = sel[1];
    __syncthreads();

    hist[t] = 0; __syncthreads();
    for (int i = t; i < cnt; i += 256) {
      unsigned b = __float_as_uint(cbuf[i]);
      if (((b >> 8) & 255u) == (unsigned)b1) atomicAdd(&hist[b & 255u], 1);
    }
    __syncthreads();
    h = hist[t];
    suf = suffix_scan_256(h, sh);
    above = suf - h;
    if (suf >= rem1 && above < rem1) { sel[0] = t; }
    __syncthreads();
    int b0 = sel[0];
    __syncthreads();

    unsigned tbits = ((unsigned)ibin << 16) | ((unsigned)b1 << 8) | (unsigned)b0;
    float tval = __uint_as_float(tbits);

    float sum_in = 0.f, cgt = 0.f;
    for (int i = t; i < cnt; i += 256) {
      unsigned b = __float_as_uint(cbuf[i]);
      if (b > tbits) { sum_in += cbuf[i]; cgt += 1.f; }
    }
    sum_in = block_sum(sum_in, red);
    cgt = block_sum(cgt, red);
    loss_neg += sum_in + ((float)rem - cgt) * tval;
  }

  if (t == 0) {
    float n_pos = cnt_pos;
    float loss_pos = (n_pos > 0.f) ? s_ce_pos : 0.f;
    float loss_tr = (loss_pos + loss_neg) / (n_pos + kf);

    float negm = (float)M - n_pos;
    float mp = s_tcl_ttm / fmaxf(n_pos, 1.f);
    float mn = s_tcl_negm / fmaxf(negm, 1.f);
    float loss_tcl = (n_pos > 0.f) ? (mp + 0.5f * mn) : 0.f;

    float loss_ct = (n_pos > 0.f) ? (0.5f * s_ttm_pp / (n_pos * 200.f)) : 0.f;

    atomicAdd(&out[0], loss_tr);
    atomicAdd(&out[1], loss_tcl);
    atomicAdd(&out[2], loss_ct);
  }
}

extern "C" void kernel_launch(void* const* d_in, const int* in_sizes, int n_in,
                              void* d_out, int out_size, void* d_ws, size_t ws_size,
                              hipStream_t stream) {
  (void)in_sizes; (void)n_in; (void)out_size; (void)ws_size;
  const float* cls3 = (const float*)d_in[0];
  const float* reg3 = (const float*)d_in[1];
  const float* gt3  = (const float*)d_in[2];
  const float* cls4 = (const float*)d_in[3];
  const float* reg4 = (const float*)d_in[4];
  const float* gt4  = (const float*)d_in[5];
  const float* cls5 = (const float*)d_in[6];
  const float* reg5 = (const float*)d_in[7];
  const float* gt5  = (const float*)d_in[8];

  float* ws = (float*)d_ws;
  float* out = (float*)d_out;
  unsigned* hist = (unsigned*)(ws + HIST_OFF);

  zero_kernel<<<192, 256, 0, stream>>>(ws, out);

  pixel_kernel<<<dim3(1250, 2), 64, 0, stream>>>(cls3, reg3, gt3, ws + 0,      ws + PART_OFF + 0 * PART_STRIDE, hist + 0 * 65536, 80000, 10000);
  pixel_kernel<<<dim3( 313, 2), 64, 0, stream>>>(cls4, reg4, gt4, ws + 80000,  ws + PART_OFF + 1 * PART_STRIDE, hist + 1 * 65536, 20000, 2500);
  pixel_kernel<<<dim3(  79, 2), 64, 0, stream>>>(cls5, reg5, gt5, ws + 100000, ws + PART_OFF + 2 * PART_STRIDE, hist + 2 * 65536,  5000, 625);

  select_bin_kernel<<<3, 256, 0, stream>>>(ws);
  compact_kernel<<<dim3(96, 3), 256, 0, stream>>>(ws);
  final_kernel<<<3, 256, 0, stream>>>(ws, out);
}

// Round 6
// 98.692 us; speedup vs baseline: 1.3389x; 1.3389x over previous
//
#include <hip/hip_runtime.h>
#include <math.h>

#define DEVI __device__ __forceinline__

static constexpr float KD[10] = {
  0.027333068345077982f,  0.029519490925774643f, -0.039134249302383094f,
  0.1993975339773936f,    0.7234076904024206f,    0.6339789634582119f,
  0.01660210576452232f,  -0.17532808990845047f,  -0.021101834024758855f,
  0.019538882735286728f};

// ---------- workspace layout (float offsets) ----------
#define CE_OFF     0         // 105000 floats (ce per pixel, 0 for non-negatives)
#define ACC_OFF    105000    // 3 x 8 floats (written by select_bin after partial-reduce)
#define SUMGT_OFF  105024    // 3 floats
#define CCNT_OFF   105027    // 3 uints
#define STATE_OFF  105030    // 3 x 8 words: [0]=ibin [1]=rem [2]=kf(float) [3]=k_take
#define HIST_OFF   105056    // 3 x 65536 uints (16B-aligned)
#define CBUF_OFF   301664    // 3 x CAP floats
#define CAP        8192
#define PART_OFF   326240    // 3 x 15000 floats (per-wave-block partials)
#define PART_STRIDE 15000    // 2500 slots x 6

#define NB3 1250
#define NB4 313
#define NB5 79

// zero hist + small state + out; replaces the slow ROCclr fillBuffer (42us for 786KB)
__global__ void zero_kernel(float* __restrict__ ws, float* __restrict__ out) {
  int i = blockIdx.x * 256 + threadIdx.x;       // 192*256 = 49152 uint4 = 196608 dwords
  uint4* h4 = (uint4*)(ws + HIST_OFF);
  h4[i] = make_uint4(0u, 0u, 0u, 0u);
  if (blockIdx.x == 0) {
    if (threadIdx.x < 56) ws[ACC_OFF + threadIdx.x] = 0.f;   // acc+sumgt+ccnt+state+pad
    if (threadIdx.x < 3) out[threadIdx.x] = 0.f;
  }
}

// waverec3 on a 20-vector + offset, accumulating smooth_l1 over the 100 outputs.
// Stage 1 materializes a1[31]; stages 2+3 fused with a 5-wide rolling window.
DEVI float recon_sl1(const float* c, float off) {
  float a1[31];
#pragma unroll
  for (int o = 0; o < 31; ++o) {
    int b = o >> 1;
    if (o & 1)
      a1[o] = KD[0]*c[b] + KD[2]*c[b+1] + KD[4]*c[b+2] + KD[6]*c[b+3] + KD[8]*c[b+4];
    else
      a1[o] = KD[1]*c[b] + KD[3]*c[b+1] + KD[5]*c[b+2] + KD[7]*c[b+3] + KD[9]*c[b+4];
  }
  float acc = 0.f;
  float w0 = 0.f, w1 = 0.f, w2 = 0.f, w3 = 0.f, w4 = 0.f;
#pragma unroll
  for (int j = 0; j < 54; ++j) {
    int b = j >> 1;
    float aj;
    if (j & 1)
      aj = KD[0]*a1[b] + KD[2]*a1[b+1] + KD[4]*a1[b+2] + KD[6]*a1[b+3] + KD[8]*a1[b+4];
    else
      aj = KD[1]*a1[b] + KD[3]*a1[b+1] + KD[5]*a1[b+2] + KD[7]*a1[b+3] + KD[9]*a1[b+4];
    w0 = w1; w1 = w2; w2 = w3; w3 = w4; w4 = aj;
    if (j >= 4) {
      float ve = KD[1]*w0 + KD[3]*w1 + KD[5]*w2 + KD[7]*w3 + KD[9]*w4 + off;
      float vo = KD[0]*w0 + KD[2]*w1 + KD[4]*w2 + KD[6]*w3 + KD[8]*w4 + off;
      float ae = fabsf(ve);
      acc += (ae < 1.f) ? 0.5f * ve * ve : ae - 0.5f;
      float ao = fabsf(vo);
      acc += (ao < 1.f) ? 0.5f * vo * vo : ao - 0.5f;
    }
  }
  return acc;
}

DEVI float wave_sum(float v) {
#pragma unroll
  for (int d = 32; d; d >>= 1) v += __shfl_down(v, d);
  return v;
}

DEVI float block_sum(float v, float* sh) {
  int lane = threadIdx.x & 63, wid = threadIdx.x >> 6;
  v = wave_sum(v);
  if (lane == 0) sh[wid] = v;
  __syncthreads();
  if (threadIdx.x == 0) {
    float s = 0.f;
    int nw = blockDim.x >> 6;
    for (int w = 0; w < nw; ++w) s += sh[w];
    sh[0] = s;
  }
  __syncthreads();
  float r = sh[0];
  __syncthreads();
  return r;
}

// inclusive suffix sum across 256 threads; sh must be int[256]
DEVI int suffix_scan_256(int v, int* sh) {
  int t = threadIdx.x;
  sh[t] = v;
  __syncthreads();
#pragma unroll
  for (int off = 1; off < 256; off <<= 1) {
    int x = (t + off < 256) ? sh[t + off] : 0;
    __syncthreads();
    sh[t] += x;
    __syncthreads();
  }
  return sh[t];
}

// Fused over all 3 scales. 64-thread (1-wave) blocks, no LDS/barrier.
// partials per wave-block slot: [0]=cnt_pos [1]=cnt_neg [2]=sum_ce_pos
// [3]=sum_tcl_ttm [4]=sum_tcl_negm [5]=sum_ttm_pp
// blockIdx.y = axis (0: x-contour + all CE/mask work; 1: y-contour only)
__global__ void __launch_bounds__(64, 4)
pixel_kernel(const float* __restrict__ cls3, const float* __restrict__ reg3, const float* __restrict__ gt3,
             const float* __restrict__ cls4, const float* __restrict__ reg4, const float* __restrict__ gt4,
             const float* __restrict__ cls5, const float* __restrict__ reg5, const float* __restrict__ gt5,
             float* __restrict__ ws) {
  int bx = blockIdx.x, axis = blockIdx.y;
  const float *cls, *reg, *gt;
  int M, HW, ceOff, partBase, histBase, nb, lbx;
  if (bx < NB3) {
    cls = cls3; reg = reg3; gt = gt3; M = 80000; HW = 10000;
    ceOff = 0; partBase = PART_OFF; histBase = HIST_OFF; nb = NB3; lbx = bx;
  } else if (bx < NB3 + NB4) {
    cls = cls4; reg = reg4; gt = gt4; M = 20000; HW = 2500;
    ceOff = 80000; partBase = PART_OFF + PART_STRIDE; histBase = HIST_OFF + 65536; nb = NB4; lbx = bx - NB3;
  } else {
    cls = cls5; reg = reg5; gt = gt5; M = 5000; HW = 625;
    ceOff = 100000; partBase = PART_OFF + 2 * PART_STRIDE; histBase = HIST_OFF + 2 * 65536; nb = NB5; lbx = bx - NB3 - NB4;
  }
  float* ceArr = ws + ceOff;
  unsigned* hist = (unsigned*)(ws + histBase);

  int p = lbx * 64 + threadIdx.x;
  float cnt_pos = 0.f, cnt_neg = 0.f, s_ce_pos = 0.f, s_tcl_ttm = 0.f, s_tcl_negm = 0.f;
  float s_ttm_pp = 0.f;
  if (p < M) {
    int n = p / HW, hw = p % HW;
    const float* gb = gt  + (size_t)n * 45 * HW + hw;
    const float* rb = reg + (size_t)n * 42 * HW + hw;
    float tr = gb[0], train = gb[2*(size_t)HW];
    float ttm = tr * train;

    if (axis == 0) {
      const float* cb = cls + (size_t)n * 4 * HW + hw;
      float l0 = cb[0], l1 = cb[(size_t)HW], l2 = cb[2*(size_t)HW], l3 = cb[3*(size_t)HW];
      float tcl = gb[(size_t)HW];

      float m1 = fmaxf(l0, l1);
      float lse1 = m1 + logf(expf(l0 - m1) + expf(l1 - m1));
      float ce_tr = lse1 - ((tr > 0.5f) ? l1 : l0);
      float m2 = fmaxf(l2, l3);
      float lse2 = m2 + logf(expf(l2 - m2) + expf(l3 - m2));
      float ce_tcl = lse2 - ((tcl > 0.5f) ? l3 : l2);

      bool pos = ttm > 0.f;
      bool neg = ((1.f - tr) * train) > 0.f;
      float cev = neg ? ce_tr : 0.f;
      ceArr[p] = cev;
      if (neg) atomicAdd(&hist[__float_as_uint(cev) >> 16], 1u);

      cnt_pos = pos ? 1.f : 0.f;
      cnt_neg = neg ? 1.f : 0.f;
      s_ce_pos = pos ? ce_tr : 0.f;
      s_tcl_ttm = ce_tcl * ttm;
      s_tcl_negm = ce_tcl * (1.f - ttm);
    }

    // contour (this axis): linearity => reconstruct the coefficient difference
    int rc0 = (axis == 0) ? 0 : 21;
    int gc0 = (axis == 0) ? 3 : 24;
    float d[20];
#pragma unroll
    for (int c = 0; c < 20; ++c) d[c] = rb[(size_t)(rc0 + c) * HW] - gb[(size_t)(gc0 + c) * HW];
    float dc = rb[(size_t)(rc0 + 20) * HW] - gb[(size_t)(gc0 + 20) * HW];
    s_ttm_pp = ttm * recon_sl1(d, dc);
  }

  cnt_pos = wave_sum(cnt_pos);
  cnt_neg = wave_sum(cnt_neg);
  s_ce_pos = wave_sum(s_ce_pos);
  s_tcl_ttm = wave_sum(s_tcl_ttm);
  s_tcl_negm = wave_sum(s_tcl_negm);
  s_ttm_pp = wave_sum(s_ttm_pp);
  if (threadIdx.x == 0) {
    float* p6 = ws + partBase + (size_t)(axis * nb + lbx) * 6;
    p6[0] = cnt_pos; p6[1] = cnt_neg; p6[2] = s_ce_pos;
    p6[3] = s_tcl_ttm; p6[4] = s_tcl_negm; p6[5] = s_ttm_pp;
  }
}

// one block per scale: reduce partials -> acc, then find the 16-bit bin
// holding the k-th largest negative CE
__global__ void select_bin_kernel(float* __restrict__ ws) {
  int s = blockIdx.x, t = threadIdx.x;
  float* acc = ws + ACC_OFF + s * 8;
  int* st = (int*)(ws + STATE_OFF) + s * 8;
  const unsigned* hist = (const unsigned*)(ws + HIST_OFF) + s * 65536;
  const float* part = ws + PART_OFF + s * PART_STRIDE;
  int npart = (s == 0) ? 2 * NB3 : (s == 1 ? 2 * NB4 : 2 * NB5);

  __shared__ int sh[256];
  __shared__ int sel[2];
  __shared__ float red[4];

  float a0 = 0.f, a1 = 0.f, a2 = 0.f, a3 = 0.f, a4 = 0.f, a5 = 0.f;
  for (int i = t; i < npart; i += 256) {
    const float* p6 = part + (size_t)i * 6;
    a0 += p6[0]; a1 += p6[1]; a2 += p6[2]; a3 += p6[3]; a4 += p6[4]; a5 += p6[5];
  }
  a0 = block_sum(a0, red);
  a1 = block_sum(a1, red);
  a2 = block_sum(a2, red);
  a3 = block_sum(a3, red);
  a4 = block_sum(a4, red);
  a5 = block_sum(a5, red);
  if (t == 0) { acc[0] = a0; acc[1] = a1; acc[2] = a2; acc[3] = a3; acc[4] = a4; acc[5] = a5; }

  float cnt_pos = a0, cnt_negf = a1;
  int cnt_neg = (int)cnt_negf;
  float kf = (cnt_pos > 0.f) ? fminf(cnt_negf, floorf(3.f * cnt_pos)) : 100.f;
  int k_take = min((int)kf, cnt_neg);

  int ibin, rem;
  if (k_take >= cnt_neg) { ibin = -1; rem = 0; }          // take all negatives
  else if (k_take <= 0)  { ibin = 65536; rem = 0; }       // take none
  else {
    int psum = 0;
    const uint4* h4 = (const uint4*)(hist + t * 256);
#pragma unroll 8
    for (int j = 0; j < 64; ++j) { uint4 u = h4[j]; psum += (int)(u.x + u.y + u.z + u.w); }
    int suf = suffix_scan_256(psum, sh);
    int above = suf - psum;
    if (suf >= k_take && above < k_take) { sel[0] = t; sel[1] = k_take - above; }
    __syncthreads();
    int chunk = sel[0], remc = sel[1];
    __syncthreads();
    int h = (int)hist[chunk * 256 + t];
    suf = suffix_scan_256(h, sh);
    above = suf - h;
    if (suf >= remc && above < remc) { sel[0] = chunk * 256 + t; sel[1] = remc - above; }
    __syncthreads();
    ibin = sel[0]; rem = sel[1];
  }
  if (t == 0) {
    st[0] = ibin;
    st[1] = rem;
    ((float*)st)[2] = kf;
    st[3] = k_take;
  }
}

// grid-wide: sum ce strictly above bin; compact in-bin values
__global__ void compact_kernel(float* __restrict__ ws) {
  int s = blockIdx.y;
  int M   = (s == 0) ? 80000 : (s == 1 ? 20000 : 5000);
  int off = (s == 0) ? 0     : (s == 1 ? 80000 : 100000);
  const int* st = (const int*)(ws + STATE_OFF) + s * 8;
  int ibin = st[0];
  float sum = 0.f;
  __shared__ float red[4];
  if (ibin < 65536) {
    const float* ce = ws + off;
    unsigned* ccnt = (unsigned*)(ws + CCNT_OFF) + s;
    float* cbuf = ws + CBUF_OFF + s * CAP;
    for (int i = blockIdx.x * blockDim.x + threadIdx.x; i < M; i += gridDim.x * blockDim.x) {
      float v = ce[i];
      int bin = (int)(__float_as_uint(v) >> 16);
      if (bin > ibin) sum += v;
      else if (bin == ibin) {
        unsigned idx = atomicAdd(ccnt, 1u);
        if (idx < CAP) cbuf[idx] = v;
      }
    }
  }
  sum = block_sum(sum, red);
  if (threadIdx.x == 0 && sum != 0.f) atomicAdd(ws + SUMGT_OFF + s, sum);
}

// one block per scale: exact k-th value within the bin (two 8-bit LDS radix passes), assemble losses
__global__ void final_kernel(float* __restrict__ ws, float* __restrict__ out) {
  int s = blockIdx.x, t = threadIdx.x;
  int M = (s == 0) ? 80000 : (s == 1 ? 20000 : 5000);
  const float* acc = ws + ACC_OFF + s * 8;
  const int* st = (const int*)(ws + STATE_OFF) + s * 8;

  __shared__ int hist[256];
  __shared__ int sh[256];
  __shared__ int sel[2];
  __shared__ float red[8];

  float cnt_pos = acc[0];
  float s_ce_pos = acc[2], s_tcl_ttm = acc[3], s_tcl_negm = acc[4], s_ttm_pp = acc[5];
  int ibin = st[0], rem = st[1];
  float kf = ((const float*)st)[2];
  float loss_neg = ws[SUMGT_OFF + s];

  if (rem > 0) {
    int cnt = min((int)((unsigned*)(ws + CCNT_OFF))[s], CAP);
    const float* cbuf = ws + CBUF_OFF + s * CAP;

    hist[t] = 0; __syncthreads();
    for (int i = t; i < cnt; i += 256)
      atomicAdd(&hist[(__float_as_uint(cbuf[i]) >> 8) & 255u], 1);
    __syncthreads();
    int h = hist[t];
    int suf = suffix_scan_256(h, sh);
    int above = suf - h;
    if (suf >= rem && above < rem) { sel[0] = t; sel[1] = rem - above; }
    __syncthreads();
    int b1 = sel[0], rem1 = sel[1];
    __syncthreads();

    hist[t] = 0; __syncthreads();
    for (int i = t; i < cnt; i += 256) {
      unsigned b = __float_as_uint(cbuf[i]);
      if (((b >> 8) & 255u) == (unsigned)b1) atomicAdd(&hist[b & 255u], 1);
    }
    __syncthreads();
    h = hist[t];
    suf = suffix_scan_256(h, sh);
    above = suf - h;
    if (suf >= rem1 && above < rem1) { sel[0] = t; }
    __syncthreads();
    int b0 = sel[0];
    __syncthreads();

    unsigned tbits = ((unsigned)ibin << 16) | ((unsigned)b1 << 8) | (unsigned)b0;
    float tval = __uint_as_float(tbits);

    float sum_in = 0.f, cgt = 0.f;
    for (int i = t; i < cnt; i += 256) {
      unsigned b = __float_as_uint(cbuf[i]);
      if (b > tbits) { sum_in += cbuf[i]; cgt += 1.f; }
    }
    sum_in = block_sum(sum_in, red);
    cgt = block_sum(cgt, red);
    loss_neg += sum_in + ((float)rem - cgt) * tval;
  }

  if (t == 0) {
    float n_pos = cnt_pos;
    float loss_pos = (n_pos > 0.f) ? s_ce_pos : 0.f;
    float loss_tr = (loss_pos + loss_neg) / (n_pos + kf);

    float negm = (float)M - n_pos;
    float mp = s_tcl_ttm / fmaxf(n_pos, 1.f);
    float mn = s_tcl_negm / fmaxf(negm, 1.f);
    float loss_tcl = (n_pos > 0.f) ? (mp + 0.5f * mn) : 0.f;

    float loss_ct = (n_pos > 0.f) ? (0.5f * s_ttm_pp / (n_pos * 200.f)) : 0.f;

    atomicAdd(&out[0], loss_tr);
    atomicAdd(&out[1], loss_tcl);
    atomicAdd(&out[2], loss_ct);
  }
}

extern "C" void kernel_launch(void* const* d_in, const int* in_sizes, int n_in,
                              void* d_out, int out_size, void* d_ws, size_t ws_size,
                              hipStream_t stream) {
  (void)in_sizes; (void)n_in; (void)out_size; (void)ws_size;
  const float* cls3 = (const float*)d_in[0];
  const float* reg3 = (const float*)d_in[1];
  const float* gt3  = (const float*)d_in[2];
  const float* cls4 = (const float*)d_in[3];
  const float* reg4 = (const float*)d_in[4];
  const float* gt4  = (const float*)d_in[5];
  const float* cls5 = (const float*)d_in[6];
  const float* reg5 = (const float*)d_in[7];
  const float* gt5  = (const float*)d_in[8];

  float* ws = (float*)d_ws;
  float* out = (float*)d_out;

  zero_kernel<<<192, 256, 0, stream>>>(ws, out);

  pixel_kernel<<<dim3(NB3 + NB4 + NB5, 2), 64, 0, stream>>>(
      cls3, reg3, gt3, cls4, reg4, gt4, cls5, reg5, gt5, ws);

  select_bin_kernel<<<3, 256, 0, stream>>>(ws);
  compact_kernel<<<dim3(96, 3), 256, 0, stream>>>(ws);
  final_kernel<<<3, 256, 0, stream>>>(ws, out);
}

// Round 7
// 80.040 us; speedup vs baseline: 1.6509x; 1.2330x over previous
//
#include <hip/hip_runtime.h>
#include <math.h>

#define DEVI __device__ __forceinline__

static constexpr float KD[10] = {
  0.027333068345077982f,  0.029519490925774643f, -0.039134249302383094f,
  0.1993975339773936f,    0.7234076904024206f,    0.6339789634582119f,
  0.01660210576452232f,  -0.17532808990845047f,  -0.021101834024758855f,
  0.019538882735286728f};

// ---------- workspace layout (float offsets) ----------
#define CE_OFF     0         // 105000 floats (ce per pixel, 0 for non-negatives)
#define ACC_OFF    105000    // 3 x 8 floats (written by select_bin after partial-reduce)
#define SUMGT_OFF  105024    // 3 floats
#define CCNT_OFF   105027    // 3 uints
#define STATE_OFF  105030    // 3 x 8 words: [0]=ibin [1]=rem [2]=kf(float) [3]=k_take
#define HIST_OFF   105056    // 3 x 65536 uints (16B-aligned)
#define CBUF_OFF   301664    // 3 x CAP floats
#define CAP        8192
#define PART_OFF   326240    // 3 x PART_STRIDE floats (per-block partials)
#define PART_STRIDE 3840     // >= 2*NB3*6 = 3756

#define NB3 313
#define NB4 79
#define NB5 20

// zero hist + small state + out; replaces the slow ROCclr fillBuffer (42us for 786KB)
__global__ void zero_kernel(float* __restrict__ ws, float* __restrict__ out) {
  int i = blockIdx.x * 256 + threadIdx.x;       // 192*256 = 49152 uint4 = 196608 dwords
  uint4* h4 = (uint4*)(ws + HIST_OFF);
  h4[i] = make_uint4(0u, 0u, 0u, 0u);
  if (blockIdx.x == 0) {
    if (threadIdx.x < 56) ws[ACC_OFF + threadIdx.x] = 0.f;   // acc+sumgt+ccnt+state+pad
    if (threadIdx.x < 3) out[threadIdx.x] = 0.f;
  }
}

// waverec3 on a 20-vector + offset, accumulating smooth_l1 over the 100 outputs.
// FULLY STREAMING: all three IDWT stages run through 5-wide rolling windows;
// when a1[j1] completes (j1>=4) it emits a2[2(j1-4)],a2[2(j1-4)+1]; each a2
// (window full at j2>=4) emits 2 final outputs. Peak live ~= d[20]+10 window
// regs + acc -> no a1[31]/a2[54] arrays, fits a 64-VGPR budget without spill.
DEVI float recon_sl1(const float* c, float off) {
  float a1w0 = 0.f, a1w1 = 0.f, a1w2 = 0.f, a1w3 = 0.f, a1w4 = 0.f;
  float a2w0 = 0.f, a2w1 = 0.f, a2w2 = 0.f, a2w3 = 0.f, a2w4 = 0.f;
  float acc = 0.f;
#pragma unroll
  for (int j1 = 0; j1 < 31; ++j1) {
    int b = j1 >> 1;
    float a1v;
    if (j1 & 1)
      a1v = KD[0]*c[b] + KD[2]*c[b+1] + KD[4]*c[b+2] + KD[6]*c[b+3] + KD[8]*c[b+4];
    else
      a1v = KD[1]*c[b] + KD[3]*c[b+1] + KD[5]*c[b+2] + KD[7]*c[b+3] + KD[9]*c[b+4];
    a1w0 = a1w1; a1w1 = a1w2; a1w2 = a1w3; a1w3 = a1w4; a1w4 = a1v;
    if (j1 >= 4) {
#pragma unroll
      for (int t = 0; t < 2; ++t) {
        // a2[j2], j2 = 2*(j1-4)+t, uses a1[j1-4 .. j1] = a1w0..a1w4
        float a2v;
        if (t)
          a2v = KD[0]*a1w0 + KD[2]*a1w1 + KD[4]*a1w2 + KD[6]*a1w3 + KD[8]*a1w4;
        else
          a2v = KD[1]*a1w0 + KD[3]*a1w1 + KD[5]*a1w2 + KD[7]*a1w3 + KD[9]*a1w4;
        a2w0 = a2w1; a2w1 = a2w2; a2w2 = a2w3; a2w3 = a2w4; a2w4 = a2v;
        int j2 = 2 * (j1 - 4) + t;
        if (j2 >= 4) {
          // outputs o = 2*(j2-4), 2*(j2-4)+1 from a2[j2-4..j2] = a2w0..a2w4
          float ve = KD[1]*a2w0 + KD[3]*a2w1 + KD[5]*a2w2 + KD[7]*a2w3 + KD[9]*a2w4 + off;
          float vo = KD[0]*a2w0 + KD[2]*a2w1 + KD[4]*a2w2 + KD[6]*a2w3 + KD[8]*a2w4 + off;
          float ae = fabsf(ve);
          acc += (ae < 1.f) ? 0.5f * ve * ve : ae - 0.5f;
          float ao = fabsf(vo);
          acc += (ao < 1.f) ? 0.5f * vo * vo : ao - 0.5f;
        }
      }
    }
  }
  return acc;
}

DEVI float wave_sum(float v) {
#pragma unroll
  for (int d = 32; d; d >>= 1) v += __shfl_down(v, d);
  return v;
}

DEVI float block_sum(float v, float* sh) {
  int lane = threadIdx.x & 63, wid = threadIdx.x >> 6;
  v = wave_sum(v);
  if (lane == 0) sh[wid] = v;
  __syncthreads();
  if (threadIdx.x == 0) {
    float s = 0.f;
    int nw = blockDim.x >> 6;
    for (int w = 0; w < nw; ++w) s += sh[w];
    sh[0] = s;
  }
  __syncthreads();
  float r = sh[0];
  __syncthreads();
  return r;
}

// inclusive suffix sum across 256 threads; sh must be int[256]
DEVI int suffix_scan_256(int v, int* sh) {
  int t = threadIdx.x;
  sh[t] = v;
  __syncthreads();
#pragma unroll
  for (int off = 1; off < 256; off <<= 1) {
    int x = (t + off < 256) ? sh[t + off] : 0;
    __syncthreads();
    sh[t] += x;
    __syncthreads();
  }
  return sh[t];
}

// Fused over all 3 scales; 256-thread blocks, __launch_bounds__(256,2)
// (empirically the config where the allocator grants ~84 VGPRs).
// partials per block slot: [0]=cnt_pos [1]=cnt_neg [2]=sum_ce_pos
// [3]=sum_tcl_ttm [4]=sum_tcl_negm [5]=sum_ttm_pp
// blockIdx.y = axis (0: x-contour + all CE/mask work; 1: y-contour only)
__global__ void __launch_bounds__(256, 2)
pixel_kernel(const float* __restrict__ cls3, const float* __restrict__ reg3, const float* __restrict__ gt3,
             const float* __restrict__ cls4, const float* __restrict__ reg4, const float* __restrict__ gt4,
             const float* __restrict__ cls5, const float* __restrict__ reg5, const float* __restrict__ gt5,
             float* __restrict__ ws) {
  int bx = blockIdx.x, axis = blockIdx.y;
  const float *cls, *reg, *gt;
  int M, HW, ceOff, partBase, histBase, nb, lbx;
  if (bx < NB3) {
    cls = cls3; reg = reg3; gt = gt3; M = 80000; HW = 10000;
    ceOff = 0; partBase = PART_OFF; histBase = HIST_OFF; nb = NB3; lbx = bx;
  } else if (bx < NB3 + NB4) {
    cls = cls4; reg = reg4; gt = gt4; M = 20000; HW = 2500;
    ceOff = 80000; partBase = PART_OFF + PART_STRIDE; histBase = HIST_OFF + 65536; nb = NB4; lbx = bx - NB3;
  } else {
    cls = cls5; reg = reg5; gt = gt5; M = 5000; HW = 625;
    ceOff = 100000; partBase = PART_OFF + 2 * PART_STRIDE; histBase = HIST_OFF + 2 * 65536; nb = NB5; lbx = bx - NB3 - NB4;
  }
  float* ceArr = ws + ceOff;
  unsigned* hist = (unsigned*)(ws + histBase);

  int p = lbx * 256 + threadIdx.x;
  float cnt_pos = 0.f, cnt_neg = 0.f, s_ce_pos = 0.f, s_tcl_ttm = 0.f, s_tcl_negm = 0.f;
  float s_ttm_pp = 0.f;
  if (p < M) {
    int n = p / HW, hw = p % HW;
    const float* gb = gt  + (size_t)n * 45 * HW + hw;
    const float* rb = reg + (size_t)n * 42 * HW + hw;
    float tr = gb[0], train = gb[2*(size_t)HW];
    float ttm = tr * train;

    if (axis == 0) {
      const float* cb = cls + (size_t)n * 4 * HW + hw;
      float l0 = cb[0], l1 = cb[(size_t)HW], l2 = cb[2*(size_t)HW], l3 = cb[3*(size_t)HW];
      float tcl = gb[(size_t)HW];

      float m1 = fmaxf(l0, l1);
      float lse1 = m1 + logf(expf(l0 - m1) + expf(l1 - m1));
      float ce_tr = lse1 - ((tr > 0.5f) ? l1 : l0);
      float m2 = fmaxf(l2, l3);
      float lse2 = m2 + logf(expf(l2 - m2) + expf(l3 - m2));
      float ce_tcl = lse2 - ((tcl > 0.5f) ? l3 : l2);

      bool pos = ttm > 0.f;
      bool neg = ((1.f - tr) * train) > 0.f;
      float cev = neg ? ce_tr : 0.f;
      ceArr[p] = cev;
      if (neg) atomicAdd(&hist[__float_as_uint(cev) >> 16], 1u);

      cnt_pos = pos ? 1.f : 0.f;
      cnt_neg = neg ? 1.f : 0.f;
      s_ce_pos = pos ? ce_tr : 0.f;
      s_tcl_ttm = ce_tcl * ttm;
      s_tcl_negm = ce_tcl * (1.f - ttm);
    }

    // contour (this axis): linearity => reconstruct the coefficient difference
    int rc0 = (axis == 0) ? 0 : 21;
    int gc0 = (axis == 0) ? 3 : 24;
    float d[20];
#pragma unroll
    for (int c = 0; c < 20; ++c) d[c] = rb[(size_t)(rc0 + c) * HW] - gb[(size_t)(gc0 + c) * HW];
    float dc = rb[(size_t)(rc0 + 20) * HW] - gb[(size_t)(gc0 + 20) * HW];
    s_ttm_pp = ttm * recon_sl1(d, dc);
  }

  __shared__ float shp[4][6];
  int lane = threadIdx.x & 63, wid = threadIdx.x >> 6;
  cnt_pos = wave_sum(cnt_pos);
  cnt_neg = wave_sum(cnt_neg);
  s_ce_pos = wave_sum(s_ce_pos);
  s_tcl_ttm = wave_sum(s_tcl_ttm);
  s_tcl_negm = wave_sum(s_tcl_negm);
  s_ttm_pp = wave_sum(s_ttm_pp);
  if (lane == 0) {
    shp[wid][0] = cnt_pos; shp[wid][1] = cnt_neg; shp[wid][2] = s_ce_pos;
    shp[wid][3] = s_tcl_ttm; shp[wid][4] = s_tcl_negm; shp[wid][5] = s_ttm_pp;
  }
  __syncthreads();
  if (threadIdx.x < 6) {
    float s = shp[0][threadIdx.x] + shp[1][threadIdx.x] + shp[2][threadIdx.x] + shp[3][threadIdx.x];
    ws[partBase + (size_t)(axis * nb + lbx) * 6 + threadIdx.x] = s;
  }
}

// one block per scale: reduce partials -> acc, then find the 16-bit bin
// holding the k-th largest negative CE
__global__ void select_bin_kernel(float* __restrict__ ws) {
  int s = blockIdx.x, t = threadIdx.x;
  float* acc = ws + ACC_OFF + s * 8;
  int* st = (int*)(ws + STATE_OFF) + s * 8;
  const unsigned* hist = (const unsigned*)(ws + HIST_OFF) + s * 65536;
  const float* part = ws + PART_OFF + s * PART_STRIDE;
  int npart = (s == 0) ? 2 * NB3 : (s == 1 ? 2 * NB4 : 2 * NB5);

  __shared__ int sh[256];
  __shared__ int sel[2];
  __shared__ float red[4];

  float a0 = 0.f, a1 = 0.f, a2 = 0.f, a3 = 0.f, a4 = 0.f, a5 = 0.f;
  for (int i = t; i < npart; i += 256) {
    const float* p6 = part + (size_t)i * 6;
    a0 += p6[0]; a1 += p6[1]; a2 += p6[2]; a3 += p6[3]; a4 += p6[4]; a5 += p6[5];
  }
  a0 = block_sum(a0, red);
  a1 = block_sum(a1, red);
  a2 = block_sum(a2, red);
  a3 = block_sum(a3, red);
  a4 = block_sum(a4, red);
  a5 = block_sum(a5, red);
  if (t == 0) { acc[0] = a0; acc[1] = a1; acc[2] = a2; acc[3] = a3; acc[4] = a4; acc[5] = a5; }

  float cnt_pos = a0, cnt_negf = a1;
  int cnt_neg = (int)cnt_negf;
  float kf = (cnt_pos > 0.f) ? fminf(cnt_negf, floorf(3.f * cnt_pos)) : 100.f;
  int k_take = min((int)kf, cnt_neg);

  int ibin, rem;
  if (k_take >= cnt_neg) { ibin = -1; rem = 0; }          // take all negatives
  else if (k_take <= 0)  { ibin = 65536; rem = 0; }       // take none
  else {
    int psum = 0;
    const uint4* h4 = (const uint4*)(hist + t * 256);
#pragma unroll 8
    for (int j = 0; j < 64; ++j) { uint4 u = h4[j]; psum += (int)(u.x + u.y + u.z + u.w); }
    int suf = suffix_scan_256(psum, sh);
    int above = suf - psum;
    if (suf >= k_take && above < k_take) { sel[0] = t; sel[1] = k_take - above; }
    __syncthreads();
    int chunk = sel[0], remc = sel[1];
    __syncthreads();
    int h = (int)hist[chunk * 256 + t];
    suf = suffix_scan_256(h, sh);
    above = suf - h;
    if (suf >= remc && above < remc) { sel[0] = chunk * 256 + t; sel[1] = remc - above; }
    __syncthreads();
    ibin = sel[0]; rem = sel[1];
  }
  if (t == 0) {
    st[0] = ibin;
    st[1] = rem;
    ((float*)st)[2] = kf;
    st[3] = k_take;
  }
}

// grid-wide: sum ce strictly above bin; compact in-bin values
__global__ void compact_kernel(float* __restrict__ ws) {
  int s = blockIdx.y;
  int M   = (s == 0) ? 80000 : (s == 1 ? 20000 : 5000);
  int off = (s == 0) ? 0     : (s == 1 ? 80000 : 100000);
  const int* st = (const int*)(ws + STATE_OFF) + s * 8;
  int ibin = st[0];
  float sum = 0.f;
  __shared__ float red[4];
  if (ibin < 65536) {
    const float* ce = ws + off;
    unsigned* ccnt = (unsigned*)(ws + CCNT_OFF) + s;
    float* cbuf = ws + CBUF_OFF + s * CAP;
    for (int i = blockIdx.x * blockDim.x + threadIdx.x; i < M; i += gridDim.x * blockDim.x) {
      float v = ce[i];
      int bin = (int)(__float_as_uint(v) >> 16);
      if (bin > ibin) sum += v;
      else if (bin == ibin) {
        unsigned idx = atomicAdd(ccnt, 1u);
        if (idx < CAP) cbuf[idx] = v;
      }
    }
  }
  sum = block_sum(sum, red);
  if (threadIdx.x == 0 && sum != 0.f) atomicAdd(ws + SUMGT_OFF + s, sum);
}

// one block per scale: exact k-th value within the bin (two 8-bit LDS radix passes), assemble losses
__global__ void final_kernel(float* __restrict__ ws, float* __restrict__ out) {
  int s = blockIdx.x, t = threadIdx.x;
  int M = (s == 0) ? 80000 : (s == 1 ? 20000 : 5000);
  const float* acc = ws + ACC_OFF + s * 8;
  const int* st = (const int*)(ws + STATE_OFF) + s * 8;

  __shared__ int hist[256];
  __shared__ int sh[256];
  __shared__ int sel[2];
  __shared__ float red[8];

  float cnt_pos = acc[0];
  float s_ce_pos = acc[2], s_tcl_ttm = acc[3], s_tcl_negm = acc[4], s_ttm_pp = acc[5];
  int ibin = st[0], rem = st[1];
  float kf = ((const float*)st)[2];
  float loss_neg = ws[SUMGT_OFF + s];

  if (rem > 0) {
    int cnt = min((int)((unsigned*)(ws + CCNT_OFF))[s], CAP);
    const float* cbuf = ws + CBUF_OFF + s * CAP;

    hist[t] = 0; __syncthreads();
    for (int i = t; i < cnt; i += 256)
      atomicAdd(&hist[(__float_as_uint(cbuf[i]) >> 8) & 255u], 1);
    __syncthreads();
    int h = hist[t];
    int suf = suffix_scan_256(h, sh);
    int above = suf - h;
    if (suf >= rem && above < rem) { sel[0] = t; sel[1] = rem - above; }
    __syncthreads();
    int b1 = sel[0], rem1 = sel[1];
    __syncthreads();

    hist[t] = 0; __syncthreads();
    for (int i = t; i < cnt; i += 256) {
      unsigned b = __float_as_uint(cbuf[i]);
      if (((b >> 8) & 255u) == (unsigned)b1) atomicAdd(&hist[b & 255u], 1);
    }
    __syncthreads();
    h = hist[t];
    suf = suffix_scan_256(h, sh);
    above = suf - h;
    if (suf >= rem1 && above < rem1) { sel[0] = t; }
    __syncthreads();
    int b0 = sel[0];
    __syncthreads();

    unsigned tbits = ((unsigned)ibin << 16) | ((unsigned)b1 << 8) | (unsigned)b0;
    float tval = __uint_as_float(tbits);

    float sum_in = 0.f, cgt = 0.f;
    for (int i = t; i < cnt; i += 256) {
      unsigned b = __float_as_uint(cbuf[i]);
      if (b > tbits) { sum_in += cbuf[i]; cgt += 1.f; }
    }
    sum_in = block_sum(sum_in, red);
    cgt = block_sum(cgt, red);
    loss_neg += sum_in + ((float)rem - cgt) * tval;
  }

  if (t == 0) {
    float n_pos = cnt_pos;
    float loss_pos = (n_pos > 0.f) ? s_ce_pos : 0.f;
    float loss_tr = (loss_pos + loss_neg) / (n_pos + kf);

    float negm = (float)M - n_pos;
    float mp = s_tcl_ttm / fmaxf(n_pos, 1.f);
    float mn = s_tcl_negm / fmaxf(negm, 1.f);
    float loss_tcl = (n_pos > 0.f) ? (mp + 0.5f * mn) : 0.f;

    float loss_ct = (n_pos > 0.f) ? (0.5f * s_ttm_pp / (n_pos * 200.f)) : 0.f;

    atomicAdd(&out[0], loss_tr);
    atomicAdd(&out[1], loss_tcl);
    atomicAdd(&out[2], loss_ct);
  }
}

extern "C" void kernel_launch(void* const* d_in, const int* in_sizes, int n_in,
                              void* d_out, int out_size, void* d_ws, size_t ws_size,
                              hipStream_t stream) {
  (void)in_sizes; (void)n_in; (void)out_size; (void)ws_size;
  const float* cls3 = (const float*)d_in[0];
  const float* reg3 = (const float*)d_in[1];
  const float* gt3  = (const float*)d_in[2];
  const float* cls4 = (const float*)d_in[3];
  const float* reg4 = (const float*)d_in[4];
  const float* gt4  = (const float*)d_in[5];
  const float* cls5 = (const float*)d_in[6];
  const float* reg5 = (const float*)d_in[7];
  const float* gt5  = (const float*)d_in[8];

  float* ws = (float*)d_ws;
  float* out = (float*)d_out;

  zero_kernel<<<192, 256, 0, stream>>>(ws, out);

  pixel_kernel<<<dim3(NB3 + NB4 + NB5, 2), 256, 0, stream>>>(
      cls3, reg3, gt3, cls4, reg4, gt4, cls5, reg5, gt5, ws);

  select_bin_kernel<<<3, 256, 0, stream>>>(ws);
  compact_kernel<<<dim3(96, 3), 256, 0, stream>>>(ws);
  final_kernel<<<3, 256, 0, stream>>>(ws, out);
}